// Round 4
// baseline (378.672 us; speedup 1.0000x reference)
//
#include <hip/hip_runtime.h>
#include <hip/hip_bf16.h>

#define N_NODES 100000
#define N_EDGES 1600000
#define DIM 64

#define TILE 4096
#define B1 ((N_EDGES + TILE - 1) / TILE)        // 391 partition blocks
#define K1 ((N_NODES + 255) / 256)              // 391 buckets of 256 nodes
#define NCOUNTS (K1 * B1)                       // 152881
#define SCAN_BLOCK 1024
#define NSB ((NCOUNTS + SCAN_BLOCK - 1) / SCAN_BLOCK)  // 150
#define PACKB4 ((N_NODES * DIM / 4 + 255) / 256) // 6250 (exact: N*DIM = 6.4M)
#define PLACE_CAP 4736                          // bucket mean 4096, sd 64 -> +10 sigma

typedef __attribute__((ext_vector_type(8))) short bf16x8;
typedef __attribute__((ext_vector_type(4))) float f32x4;

#if defined(__has_builtin)
#if __has_builtin(__builtin_amdgcn_fdot2_f32_bf16)
#define HAVE_DOT2 1
typedef __attribute__((ext_vector_type(2))) __bf16 bf16x2v;
#endif
#endif

// ---------------- ws layout ----------------
// At      : 32 KB bf16 (combined epilogue matrix, transposed)
// cvec    : 1 KB
// records : E * 8 B  (u64 {hi=bf16x2 coef, lo=src | dst_local<<17}); written
//           bucket-grouped by partition, re-sorted to node order IN PLACE by place
// hpack   : N*DIM*4B ({bf16 hr, bf16 hi} interleaved)
// counts  : NCOUNTS ints (raw hist -> in-place BLOCK-LOCAL exclusive prefix;
//           global offset = counts[ci] + bpre[ci>>10] — consumers MUST add bpre)
// bsum/bpre : NSB ints; inc : N ints (per-node inclusive prefix)

__device__ __forceinline__ unsigned pack_bf16x2(float lo, float hi) {
  unsigned ulo = (unsigned)__hip_bfloat16_raw(__float2bfloat16(lo)).x;
  unsigned uhi = (unsigned)__hip_bfloat16_raw(__float2bfloat16(hi)).x;
  return ulo | (uhi << 16);
}
__device__ __forceinline__ float unpack_lo(unsigned u) {
  return __int_as_float((int)(u << 16));
}
__device__ __forceinline__ float unpack_hi(unsigned u) {
  return __int_as_float((int)(u & 0xFFFF0000u));
}
__device__ __forceinline__ unsigned short f2bf(float x) {
  return __hip_bfloat16_raw(__float2bfloat16(x)).x;
}

// Fused setup: pack_h (blocks 0..PACKB4-1, float4-vectorized), combined
// epilogue operator (next 64 blocks), per-(bucket,block) histogram (last B1).
__global__ __launch_bounds__(256) void setup_fused_kernel(
    const float* __restrict__ h_real, const float* __restrict__ h_imag,
    unsigned* __restrict__ hpack, const float* __restrict__ W1,
    const float* __restrict__ b1, const float* __restrict__ W2,
    const float* __restrict__ b2, unsigned short* __restrict__ At,
    float* __restrict__ cvec, const int* __restrict__ dst,
    int* __restrict__ counts) {
  const int bid = blockIdx.x;
  const int tid = threadIdx.x;
  if (bid < PACKB4) {
    const int i = bid * 256 + tid;  // covers N*DIM/4 exactly
    const float4 hr = ((const float4*)h_real)[i];
    const float4 hi = ((const float4*)h_imag)[i];
    uint4 o;
    o.x = pack_bf16x2(hr.x, hi.x);
    o.y = pack_bf16x2(hr.y, hi.y);
    o.z = pack_bf16x2(hr.z, hi.z);
    o.w = pack_bf16x2(hr.w, hi.w);
    ((uint4*)hpack)[i] = o;
    return;
  }
  if (bid < PACKB4 + 64) {
    const int idx = (bid - PACKB4) * 256 + tid;
    if (idx < 128 * 128) {
      const int n = idx >> 7, k = idx & 127;
      float v;
      if (n < 64) {
        v = (k < 64) ? W1[n * 64 + k] : -W2[n * 64 + (k - 64)];
      } else {
        const int nn = n - 64;
        if (k < 64) {
          float s = 0.0f;
          for (int j = 0; j < 64; ++j) s += W1[j * 64 + k] * W2[nn * 64 + j];
          v = s;
        } else {
          const int kk = k - 64;
          float s = 0.0f;
          for (int j = 0; j < 64; ++j) s += W2[j * 64 + kk] * W2[nn * 64 + j];
          v = W1[nn * 64 + kk] - s;
        }
      }
      At[n * 128 + k] = f2bf(v);
    }
    if (idx < 128) {
      if (idx < 64) {
        cvec[idx] = b1[idx] - b2[idx];
      } else {
        const int nn = idx - 64;
        float s = 0.0f;
        for (int j = 0; j < 64; ++j) s += (b1[j] - b2[j]) * W2[nn * 64 + j];
        cvec[idx] = s + b1[nn] + b2[nn];
      }
    }
    return;
  }
  // histogram role
  __shared__ int lh[K1];
  const int hb = bid - PACKB4 - 64;
  for (int i = tid; i < K1; i += 256) lh[i] = 0;
  __syncthreads();
  const int e0 = hb * TILE;
  const int e1 = min(e0 + TILE, N_EDGES);
  for (int e = e0 + tid; e < e1; e += 256) atomicAdd(&lh[dst[e] >> 8], 1);
  __syncthreads();
  for (int b = tid; b < K1; b += 256) counts[b * B1 + hb] = lh[b];
}

// In-place: counts -> BLOCK-LOCAL exclusive prefix; bsum[blk] = block total.
// Wave-shuffle scan: 2 barriers instead of 20.
__global__ __launch_bounds__(SCAN_BLOCK) void scan1_kernel(
    int* __restrict__ cnt, int* __restrict__ bsum) {
  __shared__ int wsum[16];
  const int tid = threadIdx.x;
  const int lane = tid & 63;
  const int w = tid >> 6;
  const int i = blockIdx.x * SCAN_BLOCK + tid;
  const int orig = (i < NCOUNTS) ? cnt[i] : 0;
  int v = orig;
#pragma unroll
  for (int off = 1; off < 64; off <<= 1) {
    int t = __shfl_up(v, off);
    if (lane >= off) v += t;
  }
  if (lane == 63) wsum[w] = v;
  __syncthreads();
  if (w == 0) {
    int s = (lane < 16) ? wsum[lane] : 0;
#pragma unroll
    for (int off = 1; off < 16; off <<= 1) {
      int t = __shfl_up(s, off);
      if (lane >= off) s += t;
    }
    if (lane < 16) wsum[lane] = s;
  }
  __syncthreads();
  const int wex = (w == 0) ? 0 : wsum[w - 1];
  if (i < NCOUNTS) cnt[i] = wex + v - orig;  // exclusive (block-local)
  if (tid == SCAN_BLOCK - 1) bsum[blockIdx.x] = wex + v;
}

// Parallel scan of the NSB block sums -> exclusive bpre.
__global__ __launch_bounds__(256) void scan2_kernel(
    const int* __restrict__ bsum, int* __restrict__ bpre) {
  __shared__ int wsum[4];
  const int tid = threadIdx.x;
  const int lane = tid & 63;
  const int w = tid >> 6;
  const int orig = (tid < NSB) ? bsum[tid] : 0;
  int v = orig;
#pragma unroll
  for (int off = 1; off < 64; off <<= 1) {
    int t = __shfl_up(v, off);
    if (lane >= off) v += t;
  }
  if (lane == 63) wsum[w] = v;
  __syncthreads();
  if (w == 0) {
    int s = (lane < 4) ? wsum[lane] : 0;
#pragma unroll
    for (int off = 1; off < 4; off <<= 1) {
      int t = __shfl_up(s, off);
      if (lane >= off) s += t;
    }
    if (lane < 4) wsum[lane] = s;
  }
  __syncthreads();
  const int wex = (w == 0) ? 0 : wsum[w - 1];
  if (tid < NSB) bpre[tid] = wex + v - orig;  // exclusive
}

// Partition: stage tile in LDS sorted by bucket, write contiguous runs.
// Global offset = coffs[ci] + bpre[ci>>10] (scan3 eliminated).
__global__ __launch_bounds__(512) void partition_kernel(
    const int* __restrict__ src, const int* __restrict__ dst,
    const float* __restrict__ dvec,
    const float* __restrict__ w_real, const float* __restrict__ w_imag,
    const int* __restrict__ coffs, const int* __restrict__ bpre,
    unsigned long long* __restrict__ records) {
  __shared__ unsigned long long stage[TILE];  // 32 KB
  __shared__ unsigned short sb[TILE];         // 8 KB
  __shared__ int lhist[512];
  __shared__ int lbase[K1];
  __shared__ int lcur[K1];
  __shared__ int gbase[K1];
  __shared__ int wsum[8];
  const int tid = threadIdx.x;
  const int lane = tid & 63;
  const int w = tid >> 6;
  const int blk = blockIdx.x;
  const int e0 = blk * TILE;
  const int cnt_t = min(TILE, N_EDGES - e0);

  lhist[tid] = 0;
  __syncthreads();
  for (int j = tid; j < cnt_t; j += 512) atomicAdd(&lhist[dst[e0 + j] >> 8], 1);
  __syncthreads();
  const int myc = lhist[tid];
  int v = myc;
#pragma unroll
  for (int off = 1; off < 64; off <<= 1) {
    int t = __shfl_up(v, off);
    if (lane >= off) v += t;
  }
  if (lane == 63) wsum[w] = v;
  __syncthreads();
  if (w == 0) {
    int s = (lane < 8) ? wsum[lane] : 0;
#pragma unroll
    for (int off = 1; off < 8; off <<= 1) {
      int t = __shfl_up(s, off);
      if (lane >= off) s += t;
    }
    if (lane < 8) wsum[lane] = s;
  }
  __syncthreads();
  const int ex = v + ((w == 0) ? 0 : wsum[w - 1]) - myc;  // exclusive
  if (tid < K1) {
    lbase[tid] = ex;
    lcur[tid] = ex;
    const int ci = tid * B1 + blk;
    gbase[tid] = coffs[ci] + bpre[ci >> 10];
  }
  __syncthreads();

  for (int j = tid; j < cnt_t; j += 512) {
    const int e = e0 + j;
    const int t = dst[e];
    const int s = src[e];
    const int b = t >> 8;
    const float ds = dvec[s];
    const unsigned lo = (unsigned)s | ((unsigned)(t & 255) << 17);
    const unsigned hi = pack_bf16x2(ds * w_real[e], ds * w_imag[e]);
    const int r = atomicAdd(&lcur[b], 1);
    stage[r] = ((unsigned long long)hi << 32) | lo;
    sb[r] = (unsigned short)b;
  }
  __syncthreads();
  for (int i = tid; i < cnt_t; i += 512) {
    const int b = sb[i];
    records[gbase[b] + (i - lbase[b])] = stage[i];
  }
}

// One block per 256-node bucket: stage region in LDS, per-node count+scan,
// re-scatter IN PLACE to node order. Also writes the global per-node prefix.
// coffs is block-local; add bpre[] to recover global bucket offsets.
__global__ __launch_bounds__(256) void place_kernel(
    unsigned long long* __restrict__ records, const int* __restrict__ coffs,
    const int* __restrict__ bpre, int* __restrict__ inc) {
  const int b = blockIdx.x;
  const int tid = threadIdx.x;
  const int lane = tid & 63;
  const int w = tid >> 6;
  const int ci0 = b * B1;
  const int bstart = coffs[ci0] + bpre[ci0 >> 10];
  int bend;
  if (b == K1 - 1) {
    bend = N_EDGES;
  } else {
    const int ci1 = (b + 1) * B1;
    bend = coffs[ci1] + bpre[ci1 >> 10];
  }
  const int cnt = min(bend - bstart, PLACE_CAP);
  const int nbase = b << 8;
  const int nn = min(256, N_NODES - nbase);

  __shared__ unsigned long long stage[PLACE_CAP];  // 37 KB
  __shared__ int ncnt[256];
  __shared__ int ncur[256];
  __shared__ int wsum[4];

  ncnt[tid] = 0;
  __syncthreads();
  for (int i = tid; i < cnt; i += 256) {
    const unsigned long long rec = records[bstart + i];
    stage[i] = rec;
    atomicAdd(&ncnt[((unsigned)rec >> 17) & 255], 1);
  }
  __syncthreads();
  const int myc = ncnt[tid];
  int v = myc;
#pragma unroll
  for (int off = 1; off < 64; off <<= 1) {
    int t = __shfl_up(v, off);
    if (lane >= off) v += t;
  }
  if (lane == 63) wsum[w] = v;
  __syncthreads();
  if (w == 0) {
    int s = (lane < 4) ? wsum[lane] : 0;
#pragma unroll
    for (int off = 1; off < 4; off <<= 1) {
      int t = __shfl_up(s, off);
      if (lane >= off) s += t;
    }
    if (lane < 4) wsum[lane] = s;
  }
  __syncthreads();
  const int incl = v + ((w == 0) ? 0 : wsum[w - 1]);
  const int base = bstart + incl - myc;
  ncur[tid] = base;
  if (tid < nn) inc[nbase + tid] = base + myc;
  __syncthreads();
  for (int i = tid; i < cnt; i += 256) {
    const unsigned long long rec = stage[i];
    const int pos = atomicAdd(&ncur[((unsigned)rec >> 17) & 255], 1);
    records[pos] = rec;
  }
}

// Fused pull + MFMA epilogue, v3: BALANCED edge distribution.
// 512 threads = 8 waves = 32 quarter-waves; block's contiguous edge range is
// split into 32 equal chunks (one per quarter) -> no per-node imbalance.
// Each quarter runs a segmented accumulation over its chunk: running f32
// partials, flushed to LDS zacc[16][128] via ds f32 atomics at node
// boundaries (mean run length 16 -> ~1.5 flushes per 8-edge chunk).
// All 8 records broadcast-loaded up front; 8 independent row gathers in
// flight (tail indices clamped to last valid edge -> no extra distinct rows).
__global__ __launch_bounds__(512, 6) void pull_fused_kernel(
    const uint2* __restrict__ records, const int* __restrict__ inc,
    const float* __restrict__ dvec, const unsigned* __restrict__ hpack,
    const unsigned short* __restrict__ At, const float* __restrict__ cvec,
    float* __restrict__ zr_out, float* __restrict__ zi_out) {
  __shared__ __align__(16) float zacc[16][128];         // 8 KB f32 accum
  __shared__ __align__(16) unsigned short zs[16][136];  // 4.25 KB bf16 staged
  const int tid = threadIdx.x;
  const int lane = tid & 63;
  const int wave = tid >> 6;   // 0..7
  const int q4 = lane >> 4;    // quarter in wave
  const int m16 = lane & 15;   // dim group: dims 4*m16 .. 4*m16+3
  const int gq = (wave << 2) | q4;  // 0..31
  const int node0 = blockIdx.x * 16;
  const int nbl = node0 & 255;

  ((f32x4*)zacc)[tid] = (f32x4){0.f, 0.f, 0.f, 0.f};
  __syncthreads();

  const int e0b = (node0 == 0) ? 0 : inc[node0 - 1];
  const int e1b = inc[node0 + 15];
  const int chunk = (e1b - e0b + 31) >> 5;
  const int qs = e0b + gq * chunk;
  const int qe = min(qs + chunk, e1b);

  const unsigned* __restrict__ hb = hpack + 4 * m16;

  float sr0 = 0.f, sr1 = 0.f, sr2 = 0.f, sr3 = 0.f;
  float si0 = 0.f, si1 = 0.f, si2 = 0.f, si3 = 0.f;
  int cur = -1;

#if HAVE_DOT2
#define DOT2(acc, w_, h_)                                                   \
  acc = __builtin_amdgcn_fdot2_f32_bf16(__builtin_bit_cast(bf16x2v, (w_)),  \
                                        __builtin_bit_cast(bf16x2v, (h_)),  \
                                        acc, false)
#else
#define DOT2(acc, w_, h_)                                                   \
  {                                                                         \
    const float _wl = unpack_lo(w_), _wh = unpack_hi(w_);                   \
    const float _hl = unpack_lo(h_), _hh = unpack_hi(h_);                   \
    acc += _wl * _hl + _wh * _hh;                                           \
  }
#endif

#define FLUSH_ACC()                                                         \
  {                                                                         \
    float* zp = &zacc[cur][m16 * 4];                                        \
    atomicAdd(zp + 0, sr0);                                                 \
    atomicAdd(zp + 1, sr1);                                                 \
    atomicAdd(zp + 2, sr2);                                                 \
    atomicAdd(zp + 3, sr3);                                                 \
    atomicAdd(zp + 64, si0);                                                \
    atomicAdd(zp + 65, si1);                                                \
    atomicAdd(zp + 66, si2);                                                \
    atomicAdd(zp + 67, si3);                                                \
  }

#define STEP(RJ, HJ, JJ)                                                    \
  {                                                                         \
    const bool v_ = (base + JJ) < qe;                                       \
    const int nl_ = v_ ? (int)(((RJ).x >> 17) & 255) - nbl : cur;           \
    if (nl_ != cur) {                                                       \
      if (cur >= 0) FLUSH_ACC();                                            \
      sr0 = sr1 = sr2 = sr3 = si0 = si1 = si2 = si3 = 0.f;                  \
      cur = nl_;                                                            \
    }                                                                       \
    if (v_) {                                                               \
      const unsigned wneg = (RJ).y ^ 0x80000000u;                           \
      const unsigned wswp = ((RJ).y >> 16) | ((RJ).y << 16);                \
      DOT2(sr0, wneg, (HJ).x); DOT2(si0, wswp, (HJ).x);                     \
      DOT2(sr1, wneg, (HJ).y); DOT2(si1, wswp, (HJ).y);                     \
      DOT2(sr2, wneg, (HJ).z); DOT2(si2, wswp, (HJ).z);                     \
      DOT2(sr3, wneg, (HJ).w); DOT2(si3, wswp, (HJ).w);                     \
    }                                                                       \
  }

  for (int base = qs; base < qe; base += 8) {
    const int lim = qe - 1;
    const uint2 r0 = records[min(base + 0, lim)];
    const uint2 r1 = records[min(base + 1, lim)];
    const uint2 r2 = records[min(base + 2, lim)];
    const uint2 r3 = records[min(base + 3, lim)];
    const uint2 r4 = records[min(base + 4, lim)];
    const uint2 r5 = records[min(base + 5, lim)];
    const uint2 r6 = records[min(base + 6, lim)];
    const uint2 r7 = records[min(base + 7, lim)];
    const uint4 h0 = *reinterpret_cast<const uint4*>(hb + (size_t)(r0.x & 0x1FFFF) * DIM);
    const uint4 h1 = *reinterpret_cast<const uint4*>(hb + (size_t)(r1.x & 0x1FFFF) * DIM);
    const uint4 h2 = *reinterpret_cast<const uint4*>(hb + (size_t)(r2.x & 0x1FFFF) * DIM);
    const uint4 h3 = *reinterpret_cast<const uint4*>(hb + (size_t)(r3.x & 0x1FFFF) * DIM);
    const uint4 h4 = *reinterpret_cast<const uint4*>(hb + (size_t)(r4.x & 0x1FFFF) * DIM);
    const uint4 h5 = *reinterpret_cast<const uint4*>(hb + (size_t)(r5.x & 0x1FFFF) * DIM);
    const uint4 h6 = *reinterpret_cast<const uint4*>(hb + (size_t)(r6.x & 0x1FFFF) * DIM);
    const uint4 h7 = *reinterpret_cast<const uint4*>(hb + (size_t)(r7.x & 0x1FFFF) * DIM);
    STEP(r0, h0, 0)
    STEP(r1, h1, 1)
    STEP(r2, h2, 2)
    STEP(r3, h3, 3)
    STEP(r4, h4, 4)
    STEP(r5, h5, 5)
    STEP(r6, h6, 6)
    STEP(r7, h7, 7)
  }
  if (cur >= 0) FLUSH_ACC();
#undef STEP
#undef FLUSH_ACC
#undef DOT2
  __syncthreads();

  // Scale by d[n], convert to bf16 into zs. 512 threads x 4 floats = 2048.
  {
    const int idx0 = tid * 4;
    const int nd = idx0 >> 7;
    const int dd = idx0 & 127;
    const float dn = dvec[node0 + nd];
    uint2 pk;
    pk.x = pack_bf16x2(zacc[nd][dd] * dn, zacc[nd][dd + 1] * dn);
    pk.y = pack_bf16x2(zacc[nd][dd + 2] * dn, zacc[nd][dd + 3] * dn);
    *reinterpret_cast<uint2*>(&zs[nd][dd]) = pk;
  }
  __syncthreads();

  // Epilogue: Out[node][f] = sum_k Zcat[node][k]*A_comb[k][f] + cvec[f].
  // Wave t (all 8) computes feature tile [t*16, t*16+16) for all 16 nodes.
  {
    const int t = wave;
    const int m = lane & 15;
    const int q = lane >> 4;

    bf16x8 a[4];
#pragma unroll
    for (int c = 0; c < 4; ++c)
      a[c] = *reinterpret_cast<const bf16x8*>(&zs[m][c * 32 + q * 8]);

    f32x4 acc = (f32x4){0.f, 0.f, 0.f, 0.f};
    const unsigned short* brow = At + (size_t)(t * 16 + m) * 128 + q * 8;
#pragma unroll
    for (int c = 0; c < 4; ++c) {
      bf16x8 bfrag = *reinterpret_cast<const bf16x8*>(brow + c * 32);
      acc = __builtin_amdgcn_mfma_f32_16x16x32_bf16(a[c], bfrag, acc, 0, 0, 0);
    }

    const int nf = t * 16 + m;
    const float bias = cvec[nf];
    float* outp = (nf < 64) ? zr_out : zi_out;
    const int nnn = nf & 63;
#pragma unroll
    for (int r = 0; r < 4; ++r) {
      const int node = node0 + q * 4 + r;
      outp[(size_t)node * 64 + nnn] = acc[r] + bias;
    }
  }
}

extern "C" void kernel_launch(void* const* d_in, const int* in_sizes, int n_in,
                              void* d_out, int out_size, void* d_ws, size_t ws_size,
                              hipStream_t stream) {
  const float* h_real = (const float*)d_in[0];
  const float* h_imag = (const float*)d_in[1];
  const float* dvec   = (const float*)d_in[2];
  const float* w_real = (const float*)d_in[3];
  const float* w_imag = (const float*)d_in[4];
  const int*   src    = (const int*)d_in[5];
  const int*   dst    = (const int*)d_in[6];
  const float* W1     = (const float*)d_in[7];
  const float* b1     = (const float*)d_in[8];
  const float* W2     = (const float*)d_in[9];
  const float* b2     = (const float*)d_in[10];

  char* ws = (char*)d_ws;
  unsigned short* At = (unsigned short*)ws;                          // 32 KB
  float* cvec = (float*)(ws + 128 * 128 * 2);                        // 1 KB
  unsigned long long* records = (unsigned long long*)(ws + 33792);   // 12.8 MB
  unsigned* hpack = (unsigned*)(ws + 33792 + (size_t)N_EDGES * 8);   // 25.6 MB
  int* counts = (int*)(ws + 33792 + (size_t)N_EDGES * 8 + (size_t)N_NODES * DIM * 4);
  int* bsum = counts + NCOUNTS;
  int* bpre = bsum + NSB;
  int* inc  = bpre + NSB;

  float* zr_out = (float*)d_out;
  float* zi_out = zr_out + (size_t)N_NODES * DIM;

  setup_fused_kernel<<<PACKB4 + 64 + B1, 256, 0, stream>>>(
      h_real, h_imag, (unsigned*)hpack, W1, b1, W2, b2, At, cvec, dst, counts);
  scan1_kernel<<<NSB, SCAN_BLOCK, 0, stream>>>(counts, bsum);
  scan2_kernel<<<1, 256, 0, stream>>>(bsum, bpre);
  partition_kernel<<<B1, 512, 0, stream>>>(src, dst, dvec, w_real, w_imag,
                                           counts, bpre, records);
  place_kernel<<<K1, 256, 0, stream>>>(records, counts, bpre, inc);
  pull_fused_kernel<<<N_NODES / 16, 512, 0, stream>>>(
      (const uint2*)records, inc, dvec, hpack, At, cvec, zr_out, zi_out);
}